// Round 5
// baseline (107.054 us; speedup 1.0000x reference)
//
#include <hip/hip_runtime.h>

#define IN_F  4096
#define OUT_F 32000
#define KC    256          // k per tile -> 1 KB contiguous per row per tile
#define NT    (IN_F / KC)  // 16 tiles

typedef __attribute__((ext_vector_type(8))) short bf16x8;
typedef __attribute__((ext_vector_type(4))) float f32x4;

__device__ __forceinline__ short bf(float f) {
    __bf16 h = (__bf16)f;
    short s;
    __builtin_memcpy(&s, &h, 2);
    return s;
}

// Block = 256 threads (4 waves) computes 64 output channels x 16 batch.
// KC=256: each global load instruction is one wave reading ONE ROW's full
// 1-KB k-chunk (64 lanes x 16 B, perfectly contiguous -> single DRAM page,
// 8 fully-consumed lines). 16 W-loads + 4 X-loads per wave per tile.
// LDS double-buffered (80 KB -> 2 blocks/CU), XOR-swizzled rows, one
// barrier per tile, issue-early/write-late (loads for t+1 in flight across
// COMPUTE(t)).
__global__ __launch_bounds__(256) void w8a16_kernel(
    const int* __restrict__ W, const float* __restrict__ X,
    const float* __restrict__ scale, const float* __restrict__ bias,
    float* __restrict__ out)
{
    __shared__ __align__(16) short Wl[2][64][KC];  // 64 KB
    __shared__ __align__(16) short Xl[2][16][KC];  // 16 KB

    const int tid  = threadIdx.x;
    const int lane = tid & 63;
    const int wave = tid >> 6;
    const int n    = lane & 15;   // MFMA: A row (out-ch) / B row (batch)
    const int kg   = lane >> 4;   // MFMA k-group
    const int o_base = blockIdx.x * 64;

    int4   wreg[16];
    float4 xreg[4];
    f32x4  acc = {0.f, 0.f, 0.f, 0.f};

    // one instruction = one row's 1-KB chunk: lane reads 16 B at lane*16
    #define LOADR(t)                                                              \
        _Pragma("unroll")                                                         \
        for (int j = 0; j < 16; ++j) {                                            \
            const int r = wave * 16 + j;                                          \
            wreg[j] = *reinterpret_cast<const int4*>(                             \
                W + (size_t)(o_base + r) * IN_F + (t) * KC + lane * 4);           \
        }                                                                         \
        _Pragma("unroll")                                                         \
        for (int j = 0; j < 4; ++j) {                                             \
            const int r = wave * 4 + j;                                           \
            xreg[j] = *reinterpret_cast<const float4*>(                           \
                X + (size_t)r * IN_F + (t) * KC + lane * 4);                      \
        }

    #define CVT_WRITE(buf)                                                       \
        _Pragma("unroll")                                                         \
        for (int j = 0; j < 16; ++j) {                                            \
            const int r = wave * 16 + j;                                          \
            short4 v;                                                             \
            v.x = bf((float)wreg[j].x); v.y = bf((float)wreg[j].y);               \
            v.z = bf((float)wreg[j].z); v.w = bf((float)wreg[j].w);               \
            char* p = (char*)&Wl[buf][r][0] + ((lane * 8) ^ ((r & 7) << 4));      \
            *reinterpret_cast<short4*>(p) = v;                                    \
        }                                                                         \
        _Pragma("unroll")                                                         \
        for (int j = 0; j < 4; ++j) {                                             \
            const int r = wave * 4 + j;                                           \
            short4 v;                                                             \
            v.x = bf(xreg[j].x); v.y = bf(xreg[j].y);                             \
            v.z = bf(xreg[j].z); v.w = bf(xreg[j].w);                             \
            char* p = (char*)&Xl[buf][r][0] + ((lane * 8) ^ ((r & 7) << 4));      \
            *reinterpret_cast<short4*>(p) = v;                                    \
        }

    const int rA   = wave * 16 + n;
    const int swzA = (n & 7) << 4;

    #define COMPUTE(buf)                                                          \
        _Pragma("unroll")                                                         \
        for (int s = 0; s < KC / 32; ++s) {                                       \
            const int off = (s * 64 + kg * 16) ^ swzA;                            \
            bf16x8 a = *reinterpret_cast<const bf16x8*>(                          \
                (const char*)&Wl[buf][rA][0] + off);                              \
            bf16x8 b = *reinterpret_cast<const bf16x8*>(                          \
                (const char*)&Xl[buf][n][0] + off);                               \
            acc = __builtin_amdgcn_mfma_f32_16x16x32_bf16(a, b, acc, 0, 0, 0);    \
        }

    // ---- prologue ----
    LOADR(0);
    CVT_WRITE(0);
    __syncthreads();

    // ---- main loop: one barrier per tile ----
    for (int t = 0; t < NT; ++t) {
        const int cur = t & 1;
        if (t + 1 < NT) { LOADR(t + 1); }          // in flight across COMPUTE
        COMPUTE(cur);
        if (t + 1 < NT) { CVT_WRITE(cur ^ 1); }
        __syncthreads();
    }

    // ---- epilogue: D col = lane&15 (batch n), row = kg*4 + reg (out-ch) ----
    const int o = o_base + wave * 16 + kg * 4;
    const float4 sc = *reinterpret_cast<const float4*>(scale + o);
    const float4 bs = *reinterpret_cast<const float4*>(bias + o);
    float4 rr;
    rr.x = acc[0] * sc.x + bs.x;
    rr.y = acc[1] * sc.y + bs.y;
    rr.z = acc[2] * sc.z + bs.z;
    rr.w = acc[3] * sc.w + bs.w;
    *reinterpret_cast<float4*>(out + (size_t)n * OUT_F + o) = rr;

    #undef LOADR
    #undef CVT_WRITE
    #undef COMPUTE
}

extern "C" void kernel_launch(void* const* d_in, const int* in_sizes, int n_in,
                              void* d_out, int out_size, void* d_ws, size_t ws_size,
                              hipStream_t stream) {
    const float* x     = (const float*)d_in[0];
    const int*   w     = (const int*)  d_in[1];   // int8 values widened to int32 by harness
    const float* scale = (const float*)d_in[2];
    const float* bias  = (const float*)d_in[3];
    float* out = (float*)d_out;
    (void)in_sizes; (void)n_in; (void)d_ws; (void)ws_size; (void)out_size;

    w8a16_kernel<<<dim3(OUT_F / 64), dim3(256), 0, stream>>>(w, x, scale, bias, out);
}

// Round 6
// 100.444 us; speedup vs baseline: 1.0658x; 1.0658x over previous
//
#include <hip/hip_runtime.h>

#define IN_F  4096
#define OUT_F 32000
#define KC    128          // k per tile
#define NT    (IN_F / KC)  // 32 tiles (power of 2)

typedef __attribute__((ext_vector_type(8))) short bf16x8;
typedef __attribute__((ext_vector_type(4))) float f32x4;

__device__ __forceinline__ short bf(float f) {
    __bf16 h = (__bf16)f;
    short s;
    __builtin_memcpy(&s, &h, 2);
    return s;
}

// Block = 256 threads (4 waves) computes 64 output channels x 16 batch.
// R4 structure (depth-2 register prefetch, double-buffered XOR-swizzled LDS,
// one barrier per tile) + PER-BLOCK K-TILE ROTATION: block b visits k-tiles
// in order (t + b) mod 32. De-lockseps the 500 co-resident blocks so the
// machine-wide instantaneous address set covers ALL channel classes instead
// of hammering the same 16KB-strided chunk-slot in every panel at once.
__global__ __launch_bounds__(256) void w8a16_kernel(
    const int* __restrict__ W, const float* __restrict__ X,
    const float* __restrict__ scale, const float* __restrict__ bias,
    float* __restrict__ out)
{
    __shared__ __align__(16) short Wl[2][64][KC];  // 32 KB
    __shared__ __align__(16) short Xl[2][16][KC];  //  8 KB

    const int tid  = threadIdx.x;
    const int lane = tid & 63;
    const int wave = tid >> 6;
    const int n    = lane & 15;   // MFMA: A row (out-ch) / B row (batch)
    const int kg   = lane >> 4;   // MFMA k-group
    const int lo   = lane & 31;   // staging: 16-B quad within 512-B chunk
    const int hi   = lane >> 5;   // staging: row parity within instr
    const int o_base = blockIdx.x * 64;
    const int kadd   = (blockIdx.x & (NT - 1)) * KC;   // per-block k rotation

    int4   wregA[8], wregB[8];
    float4 xregA[2], xregB[2];
    f32x4  acc = {0.f, 0.f, 0.f, 0.f};

    // rotated k position for logical tile t (bijective over tiles)
    #define KPOS(t) ((((t) * KC) + kadd) & (IN_F - 1))

    #define LOADR(WR, XR, t)                                                      \
        _Pragma("unroll")                                                         \
        for (int j = 0; j < 8; ++j) {                                             \
            const int r = wave * 16 + 2 * j + hi;                                 \
            WR[j] = *reinterpret_cast<const int4*>(                               \
                W + (size_t)(o_base + r) * IN_F + KPOS(t) + lo * 4);              \
        }                                                                         \
        _Pragma("unroll")                                                         \
        for (int j = 0; j < 2; ++j) {                                             \
            const int r = wave * 4 + 2 * j + hi;                                  \
            XR[j] = *reinterpret_cast<const float4*>(                             \
                X + (size_t)r * IN_F + KPOS(t) + lo * 4);                         \
        }

    #define CVT_WRITE(WR, XR, buf)                                               \
        _Pragma("unroll")                                                         \
        for (int j = 0; j < 8; ++j) {                                             \
            const int r = wave * 16 + 2 * j + hi;                                 \
            short4 v;                                                             \
            v.x = bf((float)WR[j].x); v.y = bf((float)WR[j].y);                   \
            v.z = bf((float)WR[j].z); v.w = bf((float)WR[j].w);                   \
            char* p = (char*)&Wl[buf][r][0] + ((lo * 8) ^ ((r & 7) << 4));        \
            *reinterpret_cast<short4*>(p) = v;                                    \
        }                                                                         \
        _Pragma("unroll")                                                         \
        for (int j = 0; j < 2; ++j) {                                             \
            const int r = wave * 4 + 2 * j + hi;                                  \
            short4 v;                                                             \
            v.x = bf(XR[j].x); v.y = bf(XR[j].y);                                 \
            v.z = bf(XR[j].z); v.w = bf(XR[j].w);                                 \
            char* p = (char*)&Xl[buf][r][0] + ((lo * 8) ^ ((r & 7) << 4));        \
            *reinterpret_cast<short4*>(p) = v;                                    \
        }

    const int rA   = wave * 16 + n;
    const int swzA = (n & 7) << 4;

    #define COMPUTE(buf)                                                          \
        _Pragma("unroll")                                                         \
        for (int s = 0; s < KC / 32; ++s) {                                       \
            const int off = (s * 64 + kg * 16) ^ swzA;                            \
            bf16x8 a = *reinterpret_cast<const bf16x8*>(                          \
                (const char*)&Wl[buf][rA][0] + off);                              \
            bf16x8 b = *reinterpret_cast<const bf16x8*>(                          \
                (const char*)&Xl[buf][n][0] + off);                               \
            acc = __builtin_amdgcn_mfma_f32_16x16x32_bf16(a, b, acc, 0, 0, 0);    \
        }

    // ---- prologue: tiles 0,1 in flight; write tile 0 ----
    LOADR(wregA, xregA, 0);
    LOADR(wregB, xregB, 1);
    CVT_WRITE(wregA, xregA, 0);   // waits only on tile-0 loads (oldest)
    __syncthreads();

    // ---- main loop, unrolled x2 for static A/B role swap ----
    for (int t = 0; t < NT; t += 2) {
        if (t + 2 < NT) { LOADR(wregA, xregA, t + 2); }
        COMPUTE(0);
        if (t + 1 < NT) { CVT_WRITE(wregB, xregB, 1); }  // waits on tile t+1 loads
        __syncthreads();
        if (t + 3 < NT) { LOADR(wregB, xregB, t + 3); }
        COMPUTE(1);
        if (t + 2 < NT) { CVT_WRITE(wregA, xregA, 0); }  // waits on tile t+2 loads
        __syncthreads();
    }

    // ---- epilogue: D col = lane&15 (batch n), row = kg*4 + reg (out-ch) ----
    const int o = o_base + wave * 16 + kg * 4;
    const float4 sc = *reinterpret_cast<const float4*>(scale + o);
    const float4 bs = *reinterpret_cast<const float4*>(bias + o);
    float4 rr;
    rr.x = acc[0] * sc.x + bs.x;
    rr.y = acc[1] * sc.y + bs.y;
    rr.z = acc[2] * sc.z + bs.z;
    rr.w = acc[3] * sc.w + bs.w;
    *reinterpret_cast<float4*>(out + (size_t)n * OUT_F + o) = rr;

    #undef LOADR
    #undef CVT_WRITE
    #undef COMPUTE
    #undef KPOS
}

extern "C" void kernel_launch(void* const* d_in, const int* in_sizes, int n_in,
                              void* d_out, int out_size, void* d_ws, size_t ws_size,
                              hipStream_t stream) {
    const float* x     = (const float*)d_in[0];
    const int*   w     = (const int*)  d_in[1];   // int8 values widened to int32 by harness
    const float* scale = (const float*)d_in[2];
    const float* bias  = (const float*)d_in[3];
    float* out = (float*)d_out;
    (void)in_sizes; (void)n_in; (void)d_ws; (void)ws_size; (void)out_size;

    w8a16_kernel<<<dim3(OUT_F / 64), dim3(256), 0, stream>>>(w, x, scale, bias, out);
}

// Round 7
// 98.607 us; speedup vs baseline: 1.0857x; 1.0186x over previous
//
#include <hip/hip_runtime.h>

#define IN_F  4096
#define OUT_F 32000
#define KC    128          // k per tile
#define NT    (IN_F / KC)  // 32 tiles

typedef __attribute__((ext_vector_type(8))) short bf16x8;
typedef __attribute__((ext_vector_type(4))) float f32x4;
typedef unsigned int u32;

__device__ __forceinline__ short bf(float f) {
    __bf16 h = (__bf16)f;
    short s;
    __builtin_memcpy(&s, &h, 2);
    return s;
}

// HBM -> LDS direct (16B per lane), bypassing VGPRs. LDS dest is wave-uniform
// base + lane*16 (HW constraint); per-lane global source carries the swizzle.
__device__ __forceinline__ void gload16(const void* g, void* l) {
    __builtin_amdgcn_global_load_lds(
        (const __attribute__((address_space(1))) u32*)g,
        (__attribute__((address_space(3))) u32*)l, 16, 0, 0);
}

// W-row swizzle: applied to byte offset within a row's 512-B chunk.
// Bits <<5 from r&7 plus bit<<4 from r bit3 -> fragment ds_read_b128 across
// 64 lanes lands 8 accesses on every bank (conflict-free minimum).
__device__ __forceinline__ int swzW(int r) {
    return ((r & 7) << 5) | (((r >> 3) & 1) << 4);
}

// Block = 256 threads (4 waves), 64 out-channels x 16 batch.
// W: global_load_lds raw int32, double-buffered [2][64][128] (64 KB),
//    source-pre-swizzled; int->bf16 convert fused into COMPUTE read path.
// X: reg-staged, converted to bf16 LDS [2][16][128] (8 KB), XOR <<4 swizzle.
// One barrier per tile; X loads issue BEFORE W gloads so the XWRITE vmcnt
// wait keeps all 8 W prefetch loads in flight.
__global__ __launch_bounds__(256) void w8a16_kernel(
    const int* __restrict__ W, const float* __restrict__ X,
    const float* __restrict__ scale, const float* __restrict__ bias,
    float* __restrict__ out)
{
    __shared__ __align__(16) int   Wl[2][64][KC];  // raw int32, 64 KB
    __shared__ __align__(16) short Xl[2][16][KC];  // bf16, 8 KB

    const int tid  = threadIdx.x;
    const int lane = tid & 63;
    const int wave = tid >> 6;
    const int n    = lane & 15;   // MFMA: A row (out-ch) / B row (batch)
    const int kg   = lane >> 4;   // MFMA k-group
    const int lo   = lane & 31;   // staging: 16-B quad within 512-B chunk
    const int hi   = lane >> 5;   // staging: row parity within instr
    const int o_base = blockIdx.x * 64;

    float4 xreg[2];
    f32x4  acc = {0.f, 0.f, 0.f, 0.f};

    // ---- X global loads (2 per wave) -- issue FIRST so vmcnt-wait in
    //      XWRITE leaves the 8 newer W gloads outstanding ----
    #define LOADX(t)                                                              \
        _Pragma("unroll")                                                         \
        for (int j = 0; j < 2; ++j) {                                             \
            const int r = wave * 4 + 2 * j + hi;                                  \
            xreg[j] = *reinterpret_cast<const float4*>(                           \
                X + (size_t)r * IN_F + (t) * KC + lo * 4);                        \
        }

    // ---- W: 8 x 1KB global_load_lds per wave per tile ----
    #define GLOADW(buf, t)                                                        \
        _Pragma("unroll")                                                         \
        for (int j = 0; j < 8; ++j) {                                             \
            const int r  = wave * 16 + 2 * j + hi;                                \
            const char* gp = (const char*)W                                       \
                + ((size_t)(o_base + r) * IN_F + (size_t)(t) * KC) * 4            \
                + ((lo * 16) ^ swzW(r));                                          \
            gload16(gp, &Wl[buf][wave * 16 + 2 * j][0]);                          \
        }

    #define XWRITE(buf)                                                           \
        _Pragma("unroll")                                                         \
        for (int j = 0; j < 2; ++j) {                                             \
            const int r = wave * 4 + 2 * j + hi;                                  \
            short4 v;                                                             \
            v.x = bf(xreg[j].x); v.y = bf(xreg[j].y);                             \
            v.z = bf(xreg[j].z); v.w = bf(xreg[j].w);                             \
            char* p = (char*)&Xl[buf][r][0] + ((lo * 8) ^ ((r & 7) << 4));        \
            *reinterpret_cast<short4*>(p) = v;                                    \
        }

    const int rA    = wave * 16 + n;
    const int swzA  = swzW(rA);            // rA&7 == n&7, rA>>3 bit == n>>3
    const int swzAx = (n & 7) << 4;        // X-side swizzle (bf16 rows, 256 B)

    #define COMPUTE(buf)                                                          \
        _Pragma("unroll")                                                         \
        for (int s = 0; s < KC / 32; ++s) {                                       \
            const int o0 = (s * 128 + kg * 32) ^ swzA;                            \
            const int4 qa = *reinterpret_cast<const int4*>(                       \
                (const char*)&Wl[buf][rA][0] + o0);                               \
            const int4 qb = *reinterpret_cast<const int4*>(                       \
                (const char*)&Wl[buf][rA][0] + (o0 ^ 16));                        \
            bf16x8 a;                                                             \
            a[0]=bf((float)qa.x); a[1]=bf((float)qa.y);                           \
            a[2]=bf((float)qa.z); a[3]=bf((float)qa.w);                           \
            a[4]=bf((float)qb.x); a[5]=bf((float)qb.y);                           \
            a[6]=bf((float)qb.z); a[7]=bf((float)qb.w);                           \
            const int ox = (s * 64 + kg * 16) ^ swzAx;                            \
            bf16x8 b = *reinterpret_cast<const bf16x8*>(                          \
                (const char*)&Xl[buf][n][0] + ox);                                \
            acc = __builtin_amdgcn_mfma_f32_16x16x32_bf16(a, b, acc, 0, 0, 0);    \
        }

    // ---- prologue ----
    LOADX(0);
    GLOADW(0, 0);
    XWRITE(0);            // waits only on the 2 X loads (8 W gloads stay out)
    __syncthreads();      // drains tile-0 W into LDS

    // ---- main loop: one barrier per tile ----
    for (int t = 0; t < NT; ++t) {
        const int cur = t & 1;
        if (t + 1 < NT) {
            LOADX(t + 1);
            GLOADW(cur ^ 1, t + 1);   // in flight across COMPUTE(cur)
        }
        COMPUTE(cur);
        if (t + 1 < NT) { XWRITE(cur ^ 1); }
        __syncthreads();
    }

    // ---- epilogue: D col = lane&15 (batch n), row = kg*4 + reg (out-ch) ----
    const int o = o_base + wave * 16 + kg * 4;
    const float4 sc = *reinterpret_cast<const float4*>(scale + o);
    const float4 bs = *reinterpret_cast<const float4*>(bias + o);
    float4 rr;
    rr.x = acc[0] * sc.x + bs.x;
    rr.y = acc[1] * sc.y + bs.y;
    rr.z = acc[2] * sc.z + bs.z;
    rr.w = acc[3] * sc.w + bs.w;
    *reinterpret_cast<float4*>(out + (size_t)n * OUT_F + o) = rr;

    #undef LOADX
    #undef GLOADW
    #undef XWRITE
    #undef COMPUTE
}

extern "C" void kernel_launch(void* const* d_in, const int* in_sizes, int n_in,
                              void* d_out, int out_size, void* d_ws, size_t ws_size,
                              hipStream_t stream) {
    const float* x     = (const float*)d_in[0];
    const int*   w     = (const int*)  d_in[1];   // int8 values widened to int32 by harness
    const float* scale = (const float*)d_in[2];
    const float* bias  = (const float*)d_in[3];
    float* out = (float*)d_out;
    (void)in_sizes; (void)n_in; (void)d_ws; (void)ws_size; (void)out_size;

    w8a16_kernel<<<dim3(OUT_F / 64), dim3(256), 0, stream>>>(w, x, scale, bias, out);
}